// Round 10
// baseline (73.079 us; speedup 1.0000x reference)
//
#include <hip/hip_runtime.h>
#include <hip/hip_bf16.h>

// TT/MPO matvec, round 10 = round 9 with the spill fixed.
//   Offline (repack2): W12[(o1,o2,k2),(i1,i2)] = sum_k1 c0*c1  (bf16 frags in ws)
//   Main (tt_main2): NB=4 b/block, 256 blocks = 1/CU; vS staged once; B-frags
//   (o1-invariant) held in fbR[4][8] = 128 VGPR; per o1: {fA0 loads} {S3 prev,
//   fa2 loaded ON-DEMAND} {fA1 loads} {S2' pure reg-MFMA} {T2 flush} {barrier}.
// Round-9 lesson: fbR hoist DID kill LDS reads (conflicts 5.4M->1.5M) but
// spilled (WRITE_SIZE 16->33MB): arch-VGPR budget is ~224 (acc->AGPR split),
// and fbR+fA+fa2 held = 276. This round: fa2 on-demand in S3 (-32 held) and
// fA0/fA1 windows split around S3 (peak ~205). #pragma unroll 1 on o1 loop.
// Fallback (ws < 2.1 MB): round-7 kernels verbatim.

typedef short bf16x8 __attribute__((ext_vector_type(8)));
typedef float f32x4 __attribute__((ext_vector_type(4)));

// ---- old (fallback) ws layout ----
#define WS_A1_OFF 0
#define WS_A0_OFF 131072
#define WS_A2_OFF 147456
#define WS_NEEDED 155648
// ---- new ws layout ----
#define WS2_W12_OFF 0              // 256 mt x 8 ks x 64 lanes x 16B = 2097152 B
#define WS2_C2_OFF  2097152        // 8 ks x 64 lanes x 16B          = 8192 B
#define WS2_NEEDED  2105344

__device__ __forceinline__ unsigned short f2bf(float f) {
    union { float f; unsigned int u; } x; x.f = f;
    unsigned int u = x.u;
    u += 0x7fffu + ((u >> 16) & 1u);   // RNE
    return (unsigned short)(u >> 16);
}

__device__ __forceinline__ unsigned int pk_bf16(float lo, float hi) {
    __hip_bfloat162 h = __float22bfloat162_rn(make_float2(lo, hi));  // RNE, lo -> [15:0]
    unsigned int r;
    __builtin_memcpy(&r, &h, 4);
    return r;
}

// =================== NEW PATH ===================

__global__ void tt_repack2(const float* __restrict__ c0,
                           const float* __restrict__ c1,
                           const float* __restrict__ c2,
                           unsigned short* __restrict__ ws) {
    if (blockIdx.x < 256) {
        int idx = blockIdx.x * 512 + threadIdx.x;   // (mt, ks, l)
        int mt = idx >> 9, ks = (idx >> 6) & 7, l = idx & 63;
        int o1 = mt >> 4, o2 = mt & 15;
        int k2 = l & 15, lg = l >> 4;
        int i1 = 2 * ks + (lg >> 1);
        int i2b = (lg & 1) * 8;
        float c0row[16];
        #pragma unroll
        for (int k1 = 0; k1 < 16; ++k1) c0row[k1] = c0[o1 * 256 + i1 * 16 + k1];
        unsigned short* dst = ws + ((size_t)(mt * 8 + ks) * 64 + l) * 8;
        #pragma unroll
        for (int j = 0; j < 8; ++j) {
            int i2 = i2b + j;
            float s = 0.f;
            #pragma unroll
            for (int k1 = 0; k1 < 16; ++k1)
                s += c0row[k1] * c1[k1 * 4096 + o2 * 256 + i2 * 16 + k2];
            dst[j] = f2bf(s);
        }
    } else {
        int t = threadIdx.x;                        // (ks, l); A-row m = o3
        int ks = t >> 6, l = t & 63;
        unsigned short* dst = ws + WS2_C2_OFF / 2 + ((size_t)ks * 64 + l) * 8;
        #pragma unroll
        for (int j = 0; j < 8; ++j) {
            int k = ks * 32 + ((l >> 4) * 8) + j;   // kappa2 = (i3,k2)
            dst[j] = f2bf(c2[(k & 15) * 256 + (l & 15) * 16 + (k >> 4)]);
        }
    }
}

// main2: 512 threads = 8 waves; NB=4; LDS 96KB -> 1 block/CU.
__global__ __launch_bounds__(512, 2) void tt_main2(
    const float* __restrict__ vg, const unsigned short* __restrict__ ws,
    float* __restrict__ outg)
{
    __shared__ unsigned short vS[16384];     // [(bl,i3) 64][kappa=(i1,i2) 256], byte ^ ((i3&7)<<4)
    __shared__ unsigned short T2[2][16384];  // ping-pong; [(bl,i3) 64][(o2,k2) 256], same swz

    const int b0  = blockIdx.x * 4;
    const int t   = threadIdx.x;
    const int w   = t >> 6;
    const int l   = t & 63;
    const int l15 = l & 15;
    const int lg  = l >> 4;

    // ---- stage vS ----
    {
        const int bl  = t >> 7;
        const int i3  = (t >> 3) & 15;
        const int i1h = t & 7;
        const float* vb = vg + (size_t)(b0 + bl) * 4096;
        const int rowbyte = (bl * 16 + i3) * 512;
        const int swz = (i3 & 7) << 4;
        #pragma unroll
        for (int q = 0; q < 4; ++q) {
            const int i1  = 2 * i1h + (q >> 1);
            const int i2b = (q & 1) * 8;
            unsigned int pk[4];
            #pragma unroll
            for (int p = 0; p < 4; ++p) {
                float lo = vb[i1 * 256 + (i2b + 2 * p)     * 16 + i3];
                float hi = vb[i1 * 256 + (i2b + 2 * p + 1) * 16 + i3];
                pk[p] = pk_bf16(lo, hi);
            }
            int byte = (rowbyte + (i1 * 16 + i2b) * 2) ^ swz;
            *(uint4*)((char*)vS + byte) = make_uint4(pk[0], pk[1], pk[2], pk[3]);
        }
    }
    __syncthreads();

    // ---- B-frags -> REGISTERS, once (o1-invariant; 32 frags = 128 VGPR) ----
    bf16x8 fbR[4][8];
    #pragma unroll
    for (int nt = 0; nt < 4; ++nt)
        #pragma unroll
        for (int ks = 0; ks < 8; ++ks) {
            int byte = ((nt * 16 + l15) * 512 + (ks * 32 + lg * 8) * 2) ^ ((l15 & 7) << 4);
            fbR[nt][ks] = *(const bf16x8*)((char*)vS + byte);   // n=i3=l15, k=kappa
        }

    const int o2a = w, o2b = w + 8;

    int curr = 0;
    #pragma unroll 1
    for (int o1 = 0; o1 < 16; ++o1) {
        // ---- window 0: issue o2a's 8 A-frag loads (latency hides under S3-prev) ----
        bf16x8 fA0[8];
        #pragma unroll
        for (int ks = 0; ks < 8; ++ks)
            fA0[ks] = *(const bf16x8*)(ws + ((size_t)((o1 * 16 + o2a) * 8 + ks) * 64 + l) * 8);

        // ---- S3 of previous o1 (waves 0..3, bl=w); fa2 loaded on-demand (L1-hot) ----
        if (o1 > 0 && w < 4) {
            const unsigned short* T2p = T2[curr ^ 1];
            f32x4 a3a = {0.f, 0.f, 0.f, 0.f};
            f32x4 a3b = {0.f, 0.f, 0.f, 0.f};
            #pragma unroll
            for (int ks3 = 0; ks3 < 8; ks3 += 2) {
                bf16x8 fa2A = *(const bf16x8*)(ws + WS2_C2_OFF / 2 + ((size_t)(ks3)     * 64 + l) * 8);
                bf16x8 fa2B = *(const bf16x8*)(ws + WS2_C2_OFF / 2 + ((size_t)(ks3 + 1) * 64 + l) * 8);
                const int i3A = 2 * ks3 + (lg >> 1);
                const int i3B = i3A + 2;
                const int k2b = (lg & 1) * 8;
                int byteA = ((w * 16 + i3A) * 512 + (l15 * 16 + k2b) * 2) ^ ((i3A & 7) << 4);
                int byteB = ((w * 16 + i3B) * 512 + (l15 * 16 + k2b) * 2) ^ ((i3B & 7) << 4);
                bf16x8 fbA = *(const bf16x8*)((char*)T2p + byteA);
                bf16x8 fbB = *(const bf16x8*)((char*)T2p + byteB);
                a3a = __builtin_amdgcn_mfma_f32_16x16x32_bf16(fa2A, fbA, a3a, 0, 0, 0);
                a3b = __builtin_amdgcn_mfma_f32_16x16x32_bf16(fa2B, fbB, a3b, 0, 0, 0);
            }
            f32x4 acc3 = a3a + a3b;
            *(f32x4*)(outg + (size_t)(b0 + w) * 4096 + (o1 - 1) * 256 + l15 * 16 + lg * 4) = acc3;
        }

        // ---- window 1: issue o2b's 8 A-frag loads ----
        bf16x8 fA1[8];
        #pragma unroll
        for (int ks = 0; ks < 8; ++ks)
            fA1[ks] = *(const bf16x8*)(ws + ((size_t)((o1 * 16 + o2b) * 8 + ks) * 64 + l) * 8);

        // ---- S2': pure {A-regs x B-regs} MFMA — zero LDS reads ----
        {
            f32x4 acc[2][4];
            #pragma unroll
            for (int mi = 0; mi < 2; ++mi)
                #pragma unroll
                for (int nt = 0; nt < 4; ++nt) acc[mi][nt] = (f32x4){0.f, 0.f, 0.f, 0.f};

            #pragma unroll
            for (int ks = 0; ks < 8; ++ks) {
                #pragma unroll
                for (int nt = 0; nt < 4; ++nt) {
                    acc[0][nt] = __builtin_amdgcn_mfma_f32_16x16x32_bf16(fA0[ks], fbR[nt][ks], acc[0][nt], 0, 0, 0);
                    acc[1][nt] = __builtin_amdgcn_mfma_f32_16x16x32_bf16(fA1[ks], fbR[nt][ks], acc[1][nt], 0, 0, 0);
                }
            }
            unsigned short* T2c = T2[curr];
            #pragma unroll
            for (int mi = 0; mi < 2; ++mi) {
                const int o2 = mi ? o2b : o2a;
                #pragma unroll
                for (int nt = 0; nt < 4; ++nt) {
                    int byte = ((nt * 16 + l15) * 512 + (o2 * 16 + lg * 4) * 2) ^ ((l15 & 7) << 4);
                    uint2 wv;
                    wv.x = pk_bf16(acc[mi][nt][0], acc[mi][nt][1]);
                    wv.y = pk_bf16(acc[mi][nt][2], acc[mi][nt][3]);
                    *(uint2*)((char*)T2c + byte) = wv;
                }
            }
        }
        __syncthreads();
        curr ^= 1;
    }

    // ---- final S3 (o1 = 15) ----
    if (w < 4) {
        const unsigned short* T2p = T2[curr ^ 1];
        f32x4 a3a = {0.f, 0.f, 0.f, 0.f};
        f32x4 a3b = {0.f, 0.f, 0.f, 0.f};
        #pragma unroll
        for (int ks3 = 0; ks3 < 8; ks3 += 2) {
            bf16x8 fa2A = *(const bf16x8*)(ws + WS2_C2_OFF / 2 + ((size_t)(ks3)     * 64 + l) * 8);
            bf16x8 fa2B = *(const bf16x8*)(ws + WS2_C2_OFF / 2 + ((size_t)(ks3 + 1) * 64 + l) * 8);
            const int i3A = 2 * ks3 + (lg >> 1);
            const int i3B = i3A + 2;
            const int k2b = (lg & 1) * 8;
            int byteA = ((w * 16 + i3A) * 512 + (l15 * 16 + k2b) * 2) ^ ((i3A & 7) << 4);
            int byteB = ((w * 16 + i3B) * 512 + (l15 * 16 + k2b) * 2) ^ ((i3B & 7) << 4);
            bf16x8 fbA = *(const bf16x8*)((char*)T2p + byteA);
            bf16x8 fbB = *(const bf16x8*)((char*)T2p + byteB);
            a3a = __builtin_amdgcn_mfma_f32_16x16x32_bf16(fa2A, fbA, a3a, 0, 0, 0);
            a3b = __builtin_amdgcn_mfma_f32_16x16x32_bf16(fa2B, fbB, a3b, 0, 0, 0);
        }
        f32x4 acc3 = a3a + a3b;
        *(f32x4*)(outg + (size_t)(b0 + w) * 4096 + 15 * 256 + l15 * 16 + lg * 4) = acc3;
    }
}

// =================== FALLBACK (round-7, passed) ===================

__global__ void tt_repack(const float* __restrict__ c0,
                          const float* __restrict__ c1,
                          const float* __restrict__ c2,
                          unsigned short* __restrict__ ws) {
    int idx = blockIdx.x * 256 + threadIdx.x;
    if (idx < 8192) {
        int o2 = idx >> 9, ks = (idx >> 6) & 7, l = idx & 63;
        int k2 = l & 15;
        unsigned short* dst = ws + ((size_t)(o2 * 8 + ks) * 64 + l) * 8;
        #pragma unroll
        for (int j = 0; j < 8; ++j) {
            int k = ks * 32 + ((l >> 4) * 8) + j;
            dst[j] = f2bf(c1[(k & 15) * 4096 + o2 * 256 + (k >> 4) * 16 + k2]);
        }
    } else if (idx < 9216) {
        int t = idx - 8192;
        int o1 = t >> 6, l = t & 63;
        unsigned short* dst = ws + WS_A0_OFF / 2 + ((size_t)o1 * 64 + l) * 8;
        #pragma unroll
        for (int j = 0; j < 8; ++j) {
            int k = ((l >> 4) * 8) + j;
            float v = (l < 32) ? c0[o1 * 256 + k * 16 + (l & 15)] : 0.f;
            dst[j] = f2bf(v);
        }
    } else if (idx < 9728) {
        int t = idx - 9216;
        int ks = t >> 6, l = t & 63;
        unsigned short* dst = ws + WS_A2_OFF / 2 + ((size_t)ks * 64 + l) * 8;
        #pragma unroll
        for (int j = 0; j < 8; ++j) {
            int k = ks * 32 + ((l >> 4) * 8) + j;
            dst[j] = f2bf(c2[(k & 15) * 256 + (l & 15) * 16 + (k >> 4)]);
        }
    }
}

template <bool PACKED>
__global__ __launch_bounds__(512, 2) void tt_main(
    const float* __restrict__ vg, const float* __restrict__ c0,
    const float* __restrict__ c1, const float* __restrict__ c2,
    const unsigned short* __restrict__ ws, float* __restrict__ outg)
{
    __shared__ unsigned short T1[16384];
    __shared__ unsigned short T2[2][16384];

    const int b = blockIdx.x;
    const int t = threadIdx.x;
    const int w = t >> 6, l = t & 63, l15 = l & 15, lg = l >> 4;
    const int mg = w >> 1, ng = w & 1;

    bf16x8 fb0[2];
    {
        const float* vb = vg + (size_t)b * 4096;
        #pragma unroll
        for (int nt = 0; nt < 2; ++nt) {
            bf16x8 f = {0, 0, 0, 0, 0, 0, 0, 0};
            if (l < 32) {
                int i2 = 2 * w + nt;
                const float* p = vb + (lg * 8) * 256 + i2 * 16 + l15;
                #pragma unroll
                for (int j = 0; j < 8; ++j) f[j] = (short)f2bf(p[j * 256]);
            }
            fb0[nt] = f;
        }
    }
    bf16x8 fa1p[32];
    if constexpr (PACKED) {
        const unsigned short* a1p = ws + (size_t)l * 8;
        #pragma unroll
        for (int rt = 0; rt < 4; ++rt)
            #pragma unroll
            for (int ks = 0; ks < 8; ++ks)
                fa1p[rt * 8 + ks] = *(const bf16x8*)(a1p + ((size_t)((4 * mg + rt) * 8 + ks)) * 512);
    } else {
        for (int rt = 0; rt < 4; ++rt)
            for (int ks = 0; ks < 8; ++ks) {
                int o2 = 4 * mg + rt;
                bf16x8 f;
                for (int j = 0; j < 8; ++j) {
                    int k = ks * 32 + lg * 8 + j;
                    f[j] = (short)f2bf(c1[(k & 15) * 4096 + o2 * 256 + (k >> 4) * 16 + l15]);
                }
                fa1p[rt * 8 + ks] = f;
            }
    }

    for (int nc = 0; nc < 4; ++nc) {
        unsigned short* T2c = T2[nc & 1];
        bf16x8 fa0p[4];
        if constexpr (PACKED) {
            #pragma unroll
            for (int mtl = 0; mtl < 4; ++mtl)
                fa0p[mtl] = *(const bf16x8*)(ws + WS_A0_OFF / 2 +
                                             ((size_t)(nc * 4 + mtl) * 64 + l) * 8);
        } else {
            for (int mtl = 0; mtl < 4; ++mtl) {
                bf16x8 f = {0, 0, 0, 0, 0, 0, 0, 0};
                if (l < 32) {
                    for (int j = 0; j < 8; ++j)
                        f[j] = (short)f2bf(c0[(nc * 4 + mtl) * 256 + (lg * 8 + j) * 16 + l15]);
                }
                fa0p[mtl] = f;
            }
        }
        #pragma unroll
        for (int mtl = 0; mtl < 4; ++mtl) {
            #pragma unroll
            for (int nt = 0; nt < 2; ++nt) {
                f32x4 z = {0.f, 0.f, 0.f, 0.f};
                f32x4 d = __builtin_amdgcn_mfma_f32_16x16x32_bf16(fa0p[mtl], fb0[nt], z, 0, 0, 0);
                const int i2 = 2 * w + nt;
                const int n  = mtl * 16 + l15;
                int byte = (n * 512 + (i2 * 16 + lg * 4) * 2) ^ ((l15 & 7) << 4);
                uint2 wv;
                wv.x = pk_bf16(d[0], d[1]);
                wv.y = pk_bf16(d[2], d[3]);
                *(uint2*)((char*)T1 + byte) = wv;
            }
        }
        __syncthreads();
        {
            f32x4 acc[4][2];
            #pragma unroll
            for (int rt = 0; rt < 4; ++rt)
                #pragma unroll
                for (int ntl = 0; ntl < 2; ++ntl) acc[rt][ntl] = (f32x4){0.f, 0.f, 0.f, 0.f};
            #pragma unroll
            for (int ks = 0; ks < 8; ++ks) {
                #pragma unroll
                for (int ntl = 0; ntl < 2; ++ntl) {
                    const int nt = 2 * ng + ntl;
                    int byte = ((nt * 16 + l15) * 512 + (ks * 32 + lg * 8) * 2) ^ ((l15 & 7) << 4);
                    bf16x8 fb = *(const bf16x8*)((char*)T1 + byte);
                    acc[0][ntl] = __builtin_amdgcn_mfma_f32_16x16x32_bf16(fa1p[0 * 8 + ks], fb, acc[0][ntl], 0, 0, 0);
                    acc[1][ntl] = __builtin_amdgcn_mfma_f32_16x16x32_bf16(fa1p[1 * 8 + ks], fb, acc[1][ntl], 0, 0, 0);
                    acc[2][ntl] = __builtin_amdgcn_mfma_f32_16x16x32_bf16(fa1p[2 * 8 + ks], fb, acc[2][ntl], 0, 0, 0);
                    acc[3][ntl] = __builtin_amdgcn_mfma_f32_16x16x32_bf16(fa1p[3 * 8 + ks], fb, acc[3][ntl], 0, 0, 0);
                }
            }
            #pragma unroll
            for (int rt = 0; rt < 4; ++rt) {
                const int o2 = 4 * mg + rt;
                #pragma unroll
                for (int ntl = 0; ntl < 2; ++ntl) {
                    const int nt = 2 * ng + ntl;
                    int byte = ((nt * 16 + o2) * 512 + (l15 * 16 + lg * 4) * 2) ^ ((o2 & 7) << 4);
                    uint2 wv;
                    wv.x = pk_bf16(acc[rt][ntl][0], acc[rt][ntl][1]);
                    wv.y = pk_bf16(acc[rt][ntl][2], acc[rt][ntl][3]);
                    *(uint2*)((char*)T2c + byte) = wv;
                }
            }
        }
        __syncthreads();
        if (w < 4) {
            bf16x8 fa2[8];
            if constexpr (PACKED) {
                #pragma unroll
                for (int ks = 0; ks < 8; ++ks)
                    fa2[ks] = *(const bf16x8*)(ws + WS_A2_OFF / 2 + ((size_t)ks * 64 + l) * 8);
            } else {
                for (int ks = 0; ks < 8; ++ks) {
                    bf16x8 f;
                    for (int j = 0; j < 8; ++j) {
                        int k = ks * 32 + lg * 8 + j;
                        f[j] = (short)f2bf(c2[(k & 15) * 256 + l15 * 16 + (k >> 4)]);
                    }
                    fa2[ks] = f;
                }
            }
            f32x4 a3a = {0.f, 0.f, 0.f, 0.f};
            f32x4 a3b = {0.f, 0.f, 0.f, 0.f};
            #pragma unroll
            for (int ks = 0; ks < 8; ks += 2) {
                int byte0 = ((w * 16 + l15) * 512 + ((ks + 0) * 32 + lg * 8) * 2) ^ ((l15 & 7) << 4);
                int byte1 = ((w * 16 + l15) * 512 + ((ks + 1) * 32 + lg * 8) * 2) ^ ((l15 & 7) << 4);
                bf16x8 fbA = *(const bf16x8*)((char*)T2c + byte0);
                bf16x8 fbB = *(const bf16x8*)((char*)T2c + byte1);
                a3a = __builtin_amdgcn_mfma_f32_16x16x32_bf16(fa2[ks],     fbA, a3a, 0, 0, 0);
                a3b = __builtin_amdgcn_mfma_f32_16x16x32_bf16(fa2[ks + 1], fbB, a3b, 0, 0, 0);
            }
            f32x4 acc3 = a3a + a3b;
            float* ob = outg + (size_t)b * 4096;
            *(f32x4*)(ob + (nc * 4 + w) * 256 + l15 * 16 + lg * 4) = acc3;
        }
    }
}

extern "C" void kernel_launch(void* const* d_in, const int* in_sizes, int n_in,
                              void* d_out, int out_size, void* d_ws, size_t ws_size,
                              hipStream_t stream) {
    const float* vg  = (const float*)d_in[0];
    const float* c0g = (const float*)d_in[1];
    const float* c1g = (const float*)d_in[2];
    const float* c2g = (const float*)d_in[3];
    float* outg = (float*)d_out;

    const int B = in_sizes[0] / 4096;

    if (ws_size >= (size_t)WS2_NEEDED && d_ws != nullptr && (B % 4) == 0) {
        tt_repack2<<<dim3(257), dim3(512), 0, stream>>>(
            c0g, c1g, c2g, (unsigned short*)d_ws);
        tt_main2<<<dim3(B / 4), dim3(512), 0, stream>>>(
            vg, (const unsigned short*)d_ws, outg);
    } else if (ws_size >= (size_t)WS_NEEDED && d_ws != nullptr) {
        tt_repack<<<dim3(38), dim3(256), 0, stream>>>(c0g, c1g, c2g, (unsigned short*)d_ws);
        tt_main<true><<<dim3(B), dim3(512), 0, stream>>>(
            vg, c0g, c1g, c2g, (const unsigned short*)d_ws, outg);
    } else {
        tt_main<false><<<dim3(B), dim3(512), 0, stream>>>(
            vg, c0g, c1g, c2g, nullptr, outg);
    }
}

// Round 11
// 54.641 us; speedup vs baseline: 1.3374x; 1.3374x over previous
//
#include <hip/hip_runtime.h>
#include <hip/hip_bf16.h>

// TT/MPO matvec, round 11 = round 8 dataflow + T4 counted-vmcnt barriers.
//   Offline (repack2): W12[(o1,o2,k2),(i1,i2)] = sum_k1 c0*c1 (bf16 frags in ws)
//   Main (tt_main2): NB=4 b/block, 256 blocks = 1/CU; vS staged once (32KB);
//   T2 ping-pong (2x32KB); per o1: {issue fA(o1+1)} {S3 prev} {S2'} {flush}
//   {lgkmcnt(0)+s_barrier WITHOUT vmcnt drain}.
// Round 8 (54us) = best dataflow; rounds 4-10 all ~54-73 because __syncthreads
// forces s_waitcnt vmcnt(0) every phase (m233 "2-phase stall" regime, ~70%
// overhead). This round: raw barrier keeps 16 A-loads in flight across phases
// (T4: counted-vs-drain0 = +38-73% per catalog); A double-buffered in statically
// named E/O register sets (rule #20), paired-body loop.
// Round-10 lessons reverted: no unroll-1, fa2 held (32 VGPR, round 8 proved ok).
// Fallback (ws < 2.1 MB): round-7 kernels verbatim.

typedef short bf16x8 __attribute__((ext_vector_type(8)));
typedef float f32x4 __attribute__((ext_vector_type(4)));

// ---- old (fallback) ws layout ----
#define WS_A1_OFF 0
#define WS_A0_OFF 131072
#define WS_A2_OFF 147456
#define WS_NEEDED 155648
// ---- new ws layout ----
#define WS2_W12_OFF 0              // 256 mt x 8 ks x 64 lanes x 16B = 2097152 B
#define WS2_C2_OFF  2097152        // 8 ks x 64 lanes x 16B          = 8192 B
#define WS2_NEEDED  2105344

// Barrier that does NOT drain vmcnt: LDS ordering via lgkmcnt(0), loads stay
// in flight. "memory" clobber pins all memory ops on their side of the asm.
#define BAR_KEEP_LOADS() asm volatile("s_waitcnt lgkmcnt(0)\n\ts_barrier" ::: "memory")

__device__ __forceinline__ unsigned short f2bf(float f) {
    union { float f; unsigned int u; } x; x.f = f;
    unsigned int u = x.u;
    u += 0x7fffu + ((u >> 16) & 1u);   // RNE
    return (unsigned short)(u >> 16);
}

__device__ __forceinline__ unsigned int pk_bf16(float lo, float hi) {
    __hip_bfloat162 h = __float22bfloat162_rn(make_float2(lo, hi));  // RNE, lo -> [15:0]
    unsigned int r;
    __builtin_memcpy(&r, &h, 4);
    return r;
}

// =================== NEW PATH ===================

__global__ void tt_repack2(const float* __restrict__ c0,
                           const float* __restrict__ c1,
                           const float* __restrict__ c2,
                           unsigned short* __restrict__ ws) {
    if (blockIdx.x < 256) {
        int idx = blockIdx.x * 512 + threadIdx.x;   // (mt, ks, l)
        int mt = idx >> 9, ks = (idx >> 6) & 7, l = idx & 63;
        int o1 = mt >> 4, o2 = mt & 15;
        int k2 = l & 15, lg = l >> 4;
        int i1 = 2 * ks + (lg >> 1);
        int i2b = (lg & 1) * 8;
        float c0row[16];
        #pragma unroll
        for (int k1 = 0; k1 < 16; ++k1) c0row[k1] = c0[o1 * 256 + i1 * 16 + k1];
        unsigned short* dst = ws + ((size_t)(mt * 8 + ks) * 64 + l) * 8;
        #pragma unroll
        for (int j = 0; j < 8; ++j) {
            int i2 = i2b + j;
            float s = 0.f;
            #pragma unroll
            for (int k1 = 0; k1 < 16; ++k1)
                s += c0row[k1] * c1[k1 * 4096 + o2 * 256 + i2 * 16 + k2];
            dst[j] = f2bf(s);
        }
    } else {
        int t = threadIdx.x;                        // (ks, l); A-row m = o3
        int ks = t >> 6, l = t & 63;
        unsigned short* dst = ws + WS2_C2_OFF / 2 + ((size_t)ks * 64 + l) * 8;
        #pragma unroll
        for (int j = 0; j < 8; ++j) {
            int k = ks * 32 + ((l >> 4) * 8) + j;   // kappa2 = (i3,k2)
            dst[j] = f2bf(c2[(k & 15) * 256 + (l & 15) * 16 + (k >> 4)]);
        }
    }
}

// One o1 phase: issue next A-loads, S3(prev), S2'(cur), flush, no-drain barrier.
__device__ __forceinline__ void tt_phase(
    int o1, int o1n,
    const unsigned short* __restrict__ ws, float* __restrict__ outg, int b0,
    int w, int l, int l15, int lg, int o2a, int o2b,
    bf16x8 (&fAc0)[8], bf16x8 (&fAc1)[8],    // current A (in flight; compiler waits)
    bf16x8 (&fAn0)[8], bf16x8 (&fAn1)[8],    // next A (issued here)
    const bf16x8 (&fa2)[8],
    const unsigned short* vS, unsigned short* T2w, const unsigned short* T2r)
{
    // 1. issue NEXT phase's 16 A-frag loads (survive the barrier: no vmcnt drain)
    #pragma unroll
    for (int ks = 0; ks < 8; ++ks) {
        fAn0[ks] = *(const bf16x8*)(ws + ((size_t)((o1n * 16 + o2a) * 8 + ks) * 64 + l) * 8);
        fAn1[ks] = *(const bf16x8*)(ws + ((size_t)((o1n * 16 + o2b) * 8 + ks) * 64 + l) * 8);
    }

    // 2. S3 of previous o1 (waves 0..3 own bl=w); waves 4-7 run ahead into S2'
    if (o1 > 0 && w < 4) {
        f32x4 a3a = {0.f, 0.f, 0.f, 0.f};
        f32x4 a3b = {0.f, 0.f, 0.f, 0.f};
        #pragma unroll
        for (int ks3 = 0; ks3 < 8; ks3 += 2) {
            const int i3A = 2 * ks3 + (lg >> 1);
            const int i3B = i3A + 2;
            const int k2b = (lg & 1) * 8;
            int byteA = ((w * 16 + i3A) * 512 + (l15 * 16 + k2b) * 2) ^ ((i3A & 7) << 4);
            int byteB = ((w * 16 + i3B) * 512 + (l15 * 16 + k2b) * 2) ^ ((i3B & 7) << 4);
            bf16x8 fbA = *(const bf16x8*)((const char*)T2r + byteA);  // n=o2=l15, k=(i3,k2)
            bf16x8 fbB = *(const bf16x8*)((const char*)T2r + byteB);
            a3a = __builtin_amdgcn_mfma_f32_16x16x32_bf16(fa2[ks3],     fbA, a3a, 0, 0, 0);
            a3b = __builtin_amdgcn_mfma_f32_16x16x32_bf16(fa2[ks3 + 1], fbB, a3b, 0, 0, 0);
        }
        f32x4 acc3 = a3a + a3b;
        *(f32x4*)(outg + (size_t)(b0 + w) * 4096 + (o1 - 1) * 256 + l15 * 16 + lg * 4) = acc3;
    }

    // 3. S2': T2w = W12[o1] x vS; wave owns o2 = {o2a, o2b}, all 4 bl
    {
        f32x4 acc[2][4];
        #pragma unroll
        for (int mi = 0; mi < 2; ++mi)
            #pragma unroll
            for (int nt = 0; nt < 4; ++nt) acc[mi][nt] = (f32x4){0.f, 0.f, 0.f, 0.f};

        #pragma unroll
        for (int ks = 0; ks < 8; ++ks) {
            #pragma unroll
            for (int nt = 0; nt < 4; ++nt) {
                int byte = ((nt * 16 + l15) * 512 + (ks * 32 + lg * 8) * 2) ^ ((l15 & 7) << 4);
                bf16x8 fb = *(const bf16x8*)((const char*)vS + byte);   // n=i3=l15, k=kappa
                acc[0][nt] = __builtin_amdgcn_mfma_f32_16x16x32_bf16(fAc0[ks], fb, acc[0][nt], 0, 0, 0);
                acc[1][nt] = __builtin_amdgcn_mfma_f32_16x16x32_bf16(fAc1[ks], fb, acc[1][nt], 0, 0, 0);
            }
        }
        // 4. flush: D row=k2=lg*4+r (consecutive), col=i3=l15; T2 row=(bl=nt,i3)
        #pragma unroll
        for (int mi = 0; mi < 2; ++mi) {
            const int o2 = mi ? o2b : o2a;
            #pragma unroll
            for (int nt = 0; nt < 4; ++nt) {
                int byte = ((nt * 16 + l15) * 512 + (o2 * 16 + lg * 4) * 2) ^ ((l15 & 7) << 4);
                uint2 wv;
                wv.x = pk_bf16(acc[mi][nt][0], acc[mi][nt][1]);
                wv.y = pk_bf16(acc[mi][nt][2], acc[mi][nt][3]);
                *(uint2*)((char*)T2w + byte) = wv;
            }
        }
    }

    // 5. barrier WITHOUT vmcnt drain: T2 visible (lgkmcnt 0), A-loads stay in flight
    BAR_KEEP_LOADS();
}

// main2: 512 threads = 8 waves; NB=4; LDS 96KB -> 1 block/CU.
__global__ __launch_bounds__(512, 2) void tt_main2(
    const float* __restrict__ vg, const unsigned short* __restrict__ ws,
    float* __restrict__ outg)
{
    __shared__ unsigned short vS[16384];     // [(bl,i3) 64][kappa=(i1,i2) 256], byte ^ ((i3&7)<<4)
    __shared__ unsigned short T2[2][16384];  // ping-pong; [(bl,i3) 64][(o2,k2) 256], same swz

    const int b0  = blockIdx.x * 4;
    const int t   = threadIdx.x;
    const int w   = t >> 6;
    const int l   = t & 63;
    const int l15 = l & 15;
    const int lg  = l >> 4;
    const int o2a = w, o2b = w + 8;

    // ---- c2 A-frags (held; 32 VGPR — round 8 proved this fits) ----
    bf16x8 fa2[8];
    #pragma unroll
    for (int ks = 0; ks < 8; ++ks)
        fa2[ks] = *(const bf16x8*)(ws + WS2_C2_OFF / 2 + ((size_t)ks * 64 + l) * 8);

    // ---- stage vS ----
    {
        const int bl  = t >> 7;
        const int i3  = (t >> 3) & 15;
        const int i1h = t & 7;
        const float* vb = vg + (size_t)(b0 + bl) * 4096;
        const int rowbyte = (bl * 16 + i3) * 512;
        const int swz = (i3 & 7) << 4;
        #pragma unroll
        for (int q = 0; q < 4; ++q) {
            const int i1  = 2 * i1h + (q >> 1);
            const int i2b = (q & 1) * 8;
            unsigned int pk[4];
            #pragma unroll
            for (int p = 0; p < 4; ++p) {
                float lo = vb[i1 * 256 + (i2b + 2 * p)     * 16 + i3];
                float hi = vb[i1 * 256 + (i2b + 2 * p + 1) * 16 + i3];
                pk[p] = pk_bf16(lo, hi);
            }
            int byte = (rowbyte + (i1 * 16 + i2b) * 2) ^ swz;
            *(uint4*)((char*)vS + byte) = make_uint4(pk[0], pk[1], pk[2], pk[3]);
        }
    }

    // ---- prologue: issue o1=0's A loads (before the barrier; they stay in flight) ----
    bf16x8 fAE0[8], fAE1[8], fAO0[8], fAO1[8];
    #pragma unroll
    for (int ks = 0; ks < 8; ++ks) {
        fAE0[ks] = *(const bf16x8*)(ws + ((size_t)((0 * 16 + o2a) * 8 + ks) * 64 + l) * 8);
        fAE1[ks] = *(const bf16x8*)(ws + ((size_t)((0 * 16 + o2b) * 8 + ks) * 64 + l) * 8);
    }
    BAR_KEEP_LOADS();   // vS visible; fA loads NOT drained

    // ---- 16 o1 phases, paired bodies for static E/O register naming ----
    for (int o1o = 0; o1o < 16; o1o += 2) {
        tt_phase(o1o, o1o + 1, ws, outg, b0, w, l, l15, lg, o2a, o2b,
                 fAE0, fAE1, fAO0, fAO1, fa2, vS, T2[0], T2[1]);
        int o1n2 = (o1o + 2 > 15) ? 15 : (o1o + 2);   // clamp: harmless re-load at tail
        tt_phase(o1o + 1, o1n2, ws, outg, b0, w, l, l15, lg, o2a, o2b,
                 fAO0, fAO1, fAE0, fAE1, fa2, vS, T2[1], T2[0]);
    }

    // ---- final S3 (o1 = 15) reads T2[1] ----
    if (w < 4) {
        const unsigned short* T2p = T2[1];
        f32x4 a3a = {0.f, 0.f, 0.f, 0.f};
        f32x4 a3b = {0.f, 0.f, 0.f, 0.f};
        #pragma unroll
        for (int ks3 = 0; ks3 < 8; ks3 += 2) {
            const int i3A = 2 * ks3 + (lg >> 1);
            const int i3B = i3A + 2;
            const int k2b = (lg & 1) * 8;
            int byteA = ((w * 16 + i3A) * 512 + (l15 * 16 + k2b) * 2) ^ ((i3A & 7) << 4);
            int byteB = ((w * 16 + i3B) * 512 + (l15 * 16 + k2b) * 2) ^ ((i3B & 7) << 4);
            bf16x8 fbA = *(const bf16x8*)((const char*)T2p + byteA);
            bf16x8 fbB = *(const bf16x8*)((const char*)T2p + byteB);
            a3a = __builtin_amdgcn_mfma_f32_16x16x32_bf16(fa2[ks3],     fbA, a3a, 0, 0, 0);
            a3b = __builtin_amdgcn_mfma_f32_16x16x32_bf16(fa2[ks3 + 1], fbB, a3b, 0, 0, 0);
        }
        f32x4 acc3 = a3a + a3b;
        *(f32x4*)(outg + (size_t)(b0 + w) * 4096 + 15 * 256 + l15 * 16 + lg * 4) = acc3;
    }
}

// =================== FALLBACK (round-7, passed) ===================

__global__ void tt_repack(const float* __restrict__ c0,
                          const float* __restrict__ c1,
                          const float* __restrict__ c2,
                          unsigned short* __restrict__ ws) {
    int idx = blockIdx.x * 256 + threadIdx.x;
    if (idx < 8192) {
        int o2 = idx >> 9, ks = (idx >> 6) & 7, l = idx & 63;
        int k2 = l & 15;
        unsigned short* dst = ws + ((size_t)(o2 * 8 + ks) * 64 + l) * 8;
        #pragma unroll
        for (int j = 0; j < 8; ++j) {
            int k = ks * 32 + ((l >> 4) * 8) + j;
            dst[j] = f2bf(c1[(k & 15) * 4096 + o2 * 256 + (k >> 4) * 16 + k2]);
        }
    } else if (idx < 9216) {
        int t = idx - 8192;
        int o1 = t >> 6, l = t & 63;
        unsigned short* dst = ws + WS_A0_OFF / 2 + ((size_t)o1 * 64 + l) * 8;
        #pragma unroll
        for (int j = 0; j < 8; ++j) {
            int k = ((l >> 4) * 8) + j;
            float v = (l < 32) ? c0[o1 * 256 + k * 16 + (l & 15)] : 0.f;
            dst[j] = f2bf(v);
        }
    } else if (idx < 9728) {
        int t = idx - 9216;
        int ks = t >> 6, l = t & 63;
        unsigned short* dst = ws + WS_A2_OFF / 2 + ((size_t)ks * 64 + l) * 8;
        #pragma unroll
        for (int j = 0; j < 8; ++j) {
            int k = ks * 32 + ((l >> 4) * 8) + j;
            dst[j] = f2bf(c2[(k & 15) * 256 + (l & 15) * 16 + (k >> 4)]);
        }
    }
}

template <bool PACKED>
__global__ __launch_bounds__(512, 2) void tt_main(
    const float* __restrict__ vg, const float* __restrict__ c0,
    const float* __restrict__ c1, const float* __restrict__ c2,
    const unsigned short* __restrict__ ws, float* __restrict__ outg)
{
    __shared__ unsigned short T1[16384];
    __shared__ unsigned short T2[2][16384];

    const int b = blockIdx.x;
    const int t = threadIdx.x;
    const int w = t >> 6, l = t & 63, l15 = l & 15, lg = l >> 4;
    const int mg = w >> 1, ng = w & 1;

    bf16x8 fb0[2];
    {
        const float* vb = vg + (size_t)b * 4096;
        #pragma unroll
        for (int nt = 0; nt < 2; ++nt) {
            bf16x8 f = {0, 0, 0, 0, 0, 0, 0, 0};
            if (l < 32) {
                int i2 = 2 * w + nt;
                const float* p = vb + (lg * 8) * 256 + i2 * 16 + l15;
                #pragma unroll
                for (int j = 0; j < 8; ++j) f[j] = (short)f2bf(p[j * 256]);
            }
            fb0[nt] = f;
        }
    }
    bf16x8 fa1p[32];
    if constexpr (PACKED) {
        const unsigned short* a1p = ws + (size_t)l * 8;
        #pragma unroll
        for (int rt = 0; rt < 4; ++rt)
            #pragma unroll
            for (int ks = 0; ks < 8; ++ks)
                fa1p[rt * 8 + ks] = *(const bf16x8*)(a1p + ((size_t)((4 * mg + rt) * 8 + ks)) * 512);
    } else {
        for (int rt = 0; rt < 4; ++rt)
            for (int ks = 0; ks < 8; ++ks) {
                int o2 = 4 * mg + rt;
                bf16x8 f;
                for (int j = 0; j < 8; ++j) {
                    int k = ks * 32 + lg * 8 + j;
                    f[j] = (short)f2bf(c1[(k & 15) * 4096 + o2 * 256 + (k >> 4) * 16 + l15]);
                }
                fa1p[rt * 8 + ks] = f;
            }
    }

    for (int nc = 0; nc < 4; ++nc) {
        unsigned short* T2c = T2[nc & 1];
        bf16x8 fa0p[4];
        if constexpr (PACKED) {
            #pragma unroll
            for (int mtl = 0; mtl < 4; ++mtl)
                fa0p[mtl] = *(const bf16x8*)(ws + WS_A0_OFF / 2 +
                                             ((size_t)(nc * 4 + mtl) * 64 + l) * 8);
        } else {
            for (int mtl = 0; mtl < 4; ++mtl) {
                bf16x8 f = {0, 0, 0, 0, 0, 0, 0, 0};
                if (l < 32) {
                    for (int j = 0; j < 8; ++j)
                        f[j] = (short)f2bf(c0[(nc * 4 + mtl) * 256 + (lg * 8 + j) * 16 + l15]);
                }
                fa0p[mtl] = f;
            }
        }
        #pragma unroll
        for (int mtl = 0; mtl < 4; ++mtl) {
            #pragma unroll
            for (int nt = 0; nt < 2; ++nt) {
                f32x4 z = {0.f, 0.f, 0.f, 0.f};
                f32x4 d = __builtin_amdgcn_mfma_f32_16x16x32_bf16(fa0p[mtl], fb0[nt], z, 0, 0, 0);
                const int i2 = 2 * w + nt;
                const int n  = mtl * 16 + l15;
                int byte = (n * 512 + (i2 * 16 + lg * 4) * 2) ^ ((l15 & 7) << 4);
                uint2 wv;
                wv.x = pk_bf16(d[0], d[1]);
                wv.y = pk_bf16(d[2], d[3]);
                *(uint2*)((char*)T1 + byte) = wv;
            }
        }
        __syncthreads();
        {
            f32x4 acc[4][2];
            #pragma unroll
            for (int rt = 0; rt < 4; ++rt)
                #pragma unroll
                for (int ntl = 0; ntl < 2; ++ntl) acc[rt][ntl] = (f32x4){0.f, 0.f, 0.f, 0.f};
            #pragma unroll
            for (int ks = 0; ks < 8; ++ks) {
                #pragma unroll
                for (int ntl = 0; ntl < 2; ++ntl) {
                    const int nt = 2 * ng + ntl;
                    int byte = ((nt * 16 + l15) * 512 + (ks * 32 + lg * 8) * 2) ^ ((l15 & 7) << 4);
                    bf16x8 fb = *(const bf16x8*)((char*)T1 + byte);
                    acc[0][ntl] = __builtin_amdgcn_mfma_f32_16x16x32_bf16(fa1p[0 * 8 + ks], fb, acc[0][ntl], 0, 0, 0);
                    acc[1][ntl] = __builtin_amdgcn_mfma_f32_16x16x32_bf16(fa1p[1 * 8 + ks], fb, acc[1][ntl], 0, 0, 0);
                    acc[2][ntl] = __builtin_amdgcn_mfma_f32_16x16x32_bf16(fa1p[2 * 8 + ks], fb, acc[2][ntl], 0, 0, 0);
                    acc[3][ntl] = __builtin_amdgcn_mfma_f32_16x16x32_bf16(fa1p[3 * 8 + ks], fb, acc[3][ntl], 0, 0, 0);
                }
            }
            #pragma unroll
            for (int rt = 0; rt < 4; ++rt) {
                const int o2 = 4 * mg + rt;
                #pragma unroll
                for (int ntl = 0; ntl < 2; ++ntl) {
                    const int nt = 2 * ng + ntl;
                    int byte = ((nt * 16 + o2) * 512 + (l15 * 16 + lg * 4) * 2) ^ ((o2 & 7) << 4);
                    uint2 wv;
                    wv.x = pk_bf16(acc[rt][ntl][0], acc[rt][ntl][1]);
                    wv.y = pk_bf16(acc[rt][ntl][2], acc[rt][ntl][3]);
                    *(uint2*)((char*)T2c + byte) = wv;
                }
            }
        }
        __syncthreads();
        if (w < 4) {
            bf16x8 fa2[8];
            if constexpr (PACKED) {
                #pragma unroll
                for (int ks = 0; ks < 8; ++ks)
                    fa2[ks] = *(const bf16x8*)(ws + WS_A2_OFF / 2 + ((size_t)ks * 64 + l) * 8);
            } else {
                for (int ks = 0; ks < 8; ++ks) {
                    bf16x8 f;
                    for (int j = 0; j < 8; ++j) {
                        int k = ks * 32 + lg * 8 + j;
                        f[j] = (short)f2bf(c2[(k & 15) * 256 + l15 * 16 + (k >> 4)]);
                    }
                    fa2[ks] = f;
                }
            }
            f32x4 a3a = {0.f, 0.f, 0.f, 0.f};
            f32x4 a3b = {0.f, 0.f, 0.f, 0.f};
            #pragma unroll
            for (int ks = 0; ks < 8; ks += 2) {
                int byte0 = ((w * 16 + l15) * 512 + ((ks + 0) * 32 + lg * 8) * 2) ^ ((l15 & 7) << 4);
                int byte1 = ((w * 16 + l15) * 512 + ((ks + 1) * 32 + lg * 8) * 2) ^ ((l15 & 7) << 4);
                bf16x8 fbA = *(const bf16x8*)((char*)T2c + byte0);
                bf16x8 fbB = *(const bf16x8*)((char*)T2c + byte1);
                a3a = __builtin_amdgcn_mfma_f32_16x16x32_bf16(fa2[ks],     fbA, a3a, 0, 0, 0);
                a3b = __builtin_amdgcn_mfma_f32_16x16x32_bf16(fa2[ks + 1], fbB, a3b, 0, 0, 0);
            }
            f32x4 acc3 = a3a + a3b;
            float* ob = outg + (size_t)b * 4096;
            *(f32x4*)(ob + (nc * 4 + w) * 256 + l15 * 16 + lg * 4) = acc3;
        }
    }
}

extern "C" void kernel_launch(void* const* d_in, const int* in_sizes, int n_in,
                              void* d_out, int out_size, void* d_ws, size_t ws_size,
                              hipStream_t stream) {
    const float* vg  = (const float*)d_in[0];
    const float* c0g = (const float*)d_in[1];
    const float* c1g = (const float*)d_in[2];
    const float* c2g = (const float*)d_in[3];
    float* outg = (float*)d_out;

    const int B = in_sizes[0] / 4096;

    if (ws_size >= (size_t)WS2_NEEDED && d_ws != nullptr && (B % 4) == 0) {
        tt_repack2<<<dim3(257), dim3(512), 0, stream>>>(
            c0g, c1g, c2g, (unsigned short*)d_ws);
        tt_main2<<<dim3(B / 4), dim3(512), 0, stream>>>(
            vg, (const unsigned short*)d_ws, outg);
    } else if (ws_size >= (size_t)WS_NEEDED && d_ws != nullptr) {
        tt_repack<<<dim3(38), dim3(256), 0, stream>>>(c0g, c1g, c2g, (unsigned short*)d_ws);
        tt_main<true><<<dim3(B), dim3(512), 0, stream>>>(
            vg, c0g, c1g, c2g, (const unsigned short*)d_ws, outg);
    } else {
        tt_main<false><<<dim3(B), dim3(512), 0, stream>>>(
            vg, c0g, c1g, c2g, nullptr, outg);
    }
}